// Round 6
// baseline (422.170 us; speedup 1.0000x reference)
//
#include <hip/hip_runtime.h>

// Problem constants
#define Bv 2
#define Hv 8
#define Lv 512
#define DKv 16
#define DMv 128          // H*DK
#define NKv 10
#define KSv 513

typedef __attribute__((ext_vector_type(8))) short short8;
typedef __attribute__((ext_vector_type(4))) float f32x4;

// chunk tables: nc_g = ceil((2^g+1)/16); chunks aligned to the END of the kernel
__device__ __constant__ int d_nc[10]     = {1,1,1,1,2,3,5,9,17,33};
__device__ __constant__ int d_cumnc[10]  = {0,1,2,3,4,6,9,14,23,40};
// total chunks = 73

// ws layout (bytes):
//   Y  : f32 [2 p][10 g][2 b][128 o][512 t]            = 10,485,760 B
//   xr : bf16 [2 p][2 b][512 t][128 i]                 =    524,288 B
//   Wb : bf16 [g][Tlocal][o][i] packed                 = 38,273,024 B
#define Y_BYTES   (10485760)
#define XR_OFF    (Y_BYTES)
#define WB_OFF    (Y_BYTES + 524288)

__device__ inline unsigned short f2bf(float f) {
    unsigned u = __float_as_uint(f);
    unsigned r = (u + 0x7FFFu + ((u >> 16) & 1u)) >> 16;
    return (unsigned short)r;
}

// ---------------------------------------------------------------------------
// fast zero-fill for Y
__global__ void zero_y(float4* __restrict__ p, int n4) {
    int stride = gridDim.x * 256;
    for (int i = blockIdx.x * 256 + threadIdx.x; i < n4; i += stride)
        p[i] = make_float4(0.f, 0.f, 0.f, 0.f);
}

// attn_out region = 1.0 (softmax over g sums to 1, even for masked entries)
__global__ void fill_ones4(float4* __restrict__ p, int n4) {
    int stride = gridDim.x * 256;
    for (int i = blockIdx.x * 256 + threadIdx.x; i < n4; i += stride)
        p[i] = make_float4(1.f, 1.f, 1.f, 1.f);
}

// ---------------------------------------------------------------------------
// xr[p][b][t][i] = bf16( flat reinterpret of Q/K [B,H,L,DK] -> [B, L, DM] )
__global__ void repack_x(const float* __restrict__ Q, const float* __restrict__ K,
                         unsigned short* __restrict__ xr) {
    int idx = blockIdx.x * 256 + threadIdx.x;        // 65536 items of 4 elems
    if (idx >= 65536) return;
    int flat = idx * 4;
    int p = flat >> 17;
    int off = flat & 131071;
    const float* src = p ? K : Q;
    float4 v = *(const float4*)(src + off);
    ushort4 o;
    o.x = f2bf(v.x); o.y = f2bf(v.y); o.z = f2bf(v.z); o.w = f2bf(v.w);
    *(ushort4*)(xr + flat) = o;
}

// ---------------------------------------------------------------------------
// Wb[g][Tlocal][o][i] bf16 <- W[g][o*128+i][513 - w_g + Tlocal], 0 if col<0.
__global__ __launch_bounds__(256) void repack_w(const float* __restrict__ W,
                                                unsigned short* __restrict__ wb) {
    int bid = blockIdx.x;
    int cid = bid >> 7;
    int o = bid & 127;                   // one output channel per block
    int g, rem = cid;
#pragma unroll
    for (g = 0; g < 10; ++g) { int nc = d_nc[g]; if (rem < nc) break; rem -= nc; }
    int cl = rem;
    int w_g = d_nc[g] * 16;
    int ccol = w_g - 16 * (cl + 1);
    int wcolbase = 513 - w_g + ccol;      // absolute W col of this chunk's tap 0

    __shared__ float tile[128][17];
    const float* wsrc = W + (size_t)g * 16384 * 513 + (size_t)o * 128 * 513;
    int tid = threadIdx.x;
    int rr = tid >> 4, cc = tid & 15;
    int col = wcolbase + cc;
    for (int r = rr; r < 128; r += 16) {          // r = i
        float v = 0.f;
        if (col >= 0) v = wsrc[(size_t)r * 513 + col];
        tile[r][cc] = v;
    }
    __syncthreads();
    unsigned short* wdst = wb + (size_t)262144 * d_cumnc[g];
    int i = tid & 127, ccw = tid >> 7;
    for (int c2 = ccw; c2 < 16; c2 += 2) {
        wdst[(size_t)(ccol + c2) * 16384 + o * 128 + i] = f2bf(tile[i][c2]);
    }
}

// ---------------------------------------------------------------------------
// conv via MFMA. A-fragments loaded straight from global (L2-resident via
// XCD swizzle) with full-tap register ping-pong prefetch; NO barriers in the
// tap loop. B (x window) in LDS with slot-rotation swizzle (conflict-free).
// 1-D grid 640: j -> r=j&7 (XCD), yy=(j>>3)&7, cid=(j>>6)*8+r.
__global__ __launch_bounds__(512, 2) void conv_mfma(const unsigned short* __restrict__ xr,
                                                    const unsigned short* __restrict__ wb,
                                                    float* __restrict__ Y) {
    int j = blockIdx.x;
    int r = j & 7, yy = (j >> 3) & 7, qq = j >> 6;
    int cid = qq * 8 + r;
    if (cid >= 73) return;
    int g, rem = cid;
#pragma unroll
    for (g = 0; g < 10; ++g) { int nc = d_nc[g]; if (rem < nc) break; rem -= nc; }
    int cl = rem;
    int w_g = d_nc[g] * 16;
    int ccol = w_g - 16 * (cl + 1);

    int p = yy >> 2, b = (yy >> 1) & 1, tt = yy & 1;
    int t0 = tt * 256;
    int pb = yy >> 1;

    int xbase = t0 + 1 - 16 * (cl + 1);    // x index of xs row 0
    if (xbase < -270) return;              // window entirely before t=0 -> all zeros

    // xs[u][kg-slot]: element (u, i) stored at u*136 + ((i>>3 + u)&15)*8 + (i&7)
    __shared__ unsigned short xs[272 * 136];

    int tid = threadIdx.x;
    int lane = tid & 63, wv = tid >> 6;
    int wm = wv >> 2, wn = wv & 3;
    int l15 = lane & 15, q = lane >> 4;

    const unsigned short* ap = wb + (size_t)262144 * d_cumnc[g] + (size_t)ccol * 16384
                               + (wm * 64 + l15) * 128 + q * 8;

    // prefetch tap 0 A-frags while staging xs
    short8 a0[4][4], a1[4][4];
#pragma unroll
    for (int mt = 0; mt < 4; ++mt)
#pragma unroll
        for (int ib = 0; ib < 4; ++ib)
            a0[mt][ib] = *(const short8*)(ap + mt * 2048 + ib * 32);

    const unsigned short* xp = xr + (size_t)pb * 65536;
    for (int e = tid; e < 272 * 16; e += 512) {
        int u = e >> 4, ic = e & 15;
        int xi = xbase + u;
        short8 v = (short8)0;
        if (xi >= 0 && xi < 512) v = *(const short8*)(xp + (size_t)xi * 128 + ic * 8);
        *(short8*)(&xs[u * 136 + ((ic + u) & 15) * 8]) = v;
    }
    __syncthreads();                        // xs ready (drains everything once)

    f32x4 acc[4][4];
#pragma unroll
    for (int mt = 0; mt < 4; ++mt)
#pragma unroll
        for (int nt = 0; nt < 4; ++nt) acc[mt][nt] = (f32x4)0.f;

#define LOADA(dst, JJ) \
    _Pragma("unroll") for (int mt = 0; mt < 4; ++mt) \
    _Pragma("unroll") for (int ib = 0; ib < 4; ++ib) \
        dst[mt][ib] = *(const short8*)(ap + (size_t)(JJ) * 16384 + mt * 2048 + ib * 32);

#define TAP(A, JJ) { \
    int row0 = wn * 64 + l15 + (JJ); \
    _Pragma("unroll") for (int ib = 0; ib < 4; ++ib) { \
        short8 bq[4]; \
        _Pragma("unroll") for (int nt = 0; nt < 4; ++nt) { \
            int row = row0 + nt * 16; \
            bq[nt] = *(const short8*)(&xs[row * 136 + ((ib * 4 + q + row) & 15) * 8]); \
        } \
        _Pragma("unroll") for (int mt = 0; mt < 4; ++mt) \
        _Pragma("unroll") for (int nt = 0; nt < 4; ++nt) \
            acc[mt][nt] = __builtin_amdgcn_mfma_f32_16x16x32_bf16( \
                A[mt][ib], bq[nt], acc[mt][nt], 0, 0, 0); \
    } }

    for (int jj = 0; jj < 16; jj += 2) {
        LOADA(a1, jj + 1);
        TAP(a0, jj);
        if (jj + 2 < 16) LOADA(a0, jj + 2);
        TAP(a1, jj + 1);
    }
#undef LOADA
#undef TAP

    // epilogue: atomic accumulate into Y[p][g][b][o][t]
    float* yp = Y + (((size_t)p * NKv + g) * 2 + b) * 65536;
    int orow = wm * 64 + q * 4;
    int tcol = t0 + wn * 64 + l15;
#pragma unroll
    for (int mt = 0; mt < 4; ++mt)
#pragma unroll
        for (int nt = 0; nt < 4; ++nt)
#pragma unroll
            for (int rr = 0; rr < 4; ++rr)
                atomicAdd(&yp[(size_t)(orow + mt * 16 + rr) * 512 + tcol + nt * 16],
                          acc[mt][nt][rr]);
}

// ---------------------------------------------------------------------------
// Masked-entry context: for masked (q,k) the scale-softmax is uniform 0.1,
// so ctx_masked[q,d] = 0.1 * sum_{k>q} S[k,d], S[k,d] = sum_g (K_p + bias).
// WRITES the out ctx region (attn_phase2 then atomicAdds unmasked parts).
__global__ __launch_bounds__(512) void suffix_ctx(const float* __restrict__ Y,
                                                  const float* __restrict__ bconv,
                                                  float* __restrict__ out) {
    int bh = blockIdx.x;        // 16
    int b = bh >> 3, h = bh & 7;
    int tid = threadIdx.x;
    int d = tid & 15;
    int s = tid >> 4;           // stripe 0..31, k in [s*16, s*16+16)

    __shared__ float tot[32][17];
    float S[16];
#pragma unroll
    for (int j = 0; j < 16; ++j) {
        int k = s * 16 + j;
        int o = h * 16 + (k >> 5);
        int t = (k & 31) * 16 + d;
        float acc = 0.f;
#pragma unroll
        for (int g = 0; g < NKv; ++g)
            acc += Y[(((size_t)(NKv + g) * 2 + b) * 65536) + (size_t)o * 512 + t]
                 + bconv[g * 128 + o];
        S[j] = acc;
    }
    float mytot = 0.f;
#pragma unroll
    for (int j = 0; j < 16; ++j) mytot += S[j];
    tot[s][d] = mytot;
    __syncthreads();
    float run = 0.f;
    for (int s2 = s + 1; s2 < 32; ++s2) run += tot[s2][d];
#pragma unroll
    for (int j = 15; j >= 0; --j) {
        int qv = s * 16 + j;
        out[(((size_t)b * 8 + h) * 512 + qv) * 16 + d] = 0.1f * run;
        run += S[j];
    }
}

// ---------------------------------------------------------------------------
// phase 2: unmasked (k<=q) part only. Block = (pair, half):
//   pair = (bh, qp): tiles qtA=qp, qtB=15-qp -> 17 kt-units, split 8/9.
//   Diagonal tile: masked lanes contribute 0 (suffix_ctx already added them).
//   ctx partials atomicAdd'ed into out (pre-written by suffix_ctx).
__global__ __launch_bounds__(256) void attn_phase2(const float* __restrict__ Y,
                                                   const float* __restrict__ bconv,
                                                   float* __restrict__ out) {
    int blk = blockIdx.x;          // 256
    int half = blk & 1;
    int pr = blk >> 1;             // 128 pairs
    int bh = pr >> 3;
    int qp = pr & 7;
    int b = bh >> 3, h = bh & 7;

    int qtA = qp, qtB = 15 - qp;
    int u0 = half ? 8 : 0, u1 = half ? 17 : 8;

    __shared__ float Qs[2][NKv * 544];   // [X][g*544 + q*17 + d]
    __shared__ float Ks[NKv * 544];      // [g*544 + k*17 + d]

    int tid = threadIdx.x;

#pragma unroll
    for (int X = 0; X < 2; ++X) {
        int o = h * 16 + (X ? qtB : qtA);
        for (int e = tid; e < NKv * 128; e += 256) {
            int g = e >> 7, c = e & 127;
            float4 v = *(const float4*)(Y + (((size_t)g * 2 + b) * 65536) +
                                        (size_t)o * 512 + c * 4);
            float bb = bconv[g * 128 + o];
            int qq = c >> 2, dd = (c & 3) * 4;
            float* qr = &Qs[X][g * 544 + qq * 17 + dd];
            qr[0] = v.x + bb; qr[1] = v.y + bb; qr[2] = v.z + bb; qr[3] = v.w + bb;
        }
    }

    int q = tid >> 3;    // 0..31
    int kl = tid & 7;    // 0..7
    float ctx[16];
#pragma unroll
    for (int d = 0; d < 16; ++d) ctx[d] = 0.f;
    int curX = (u0 <= qtA) ? 0 : 1;

    for (int u = u0; u < u1; ++u) {
        int X = (u <= qtA) ? 0 : 1;
        int qt = X ? qtB : qtA;
        int kt = X ? (u - qtA - 1) : u;

        if (X != curX) {
            int pqt = curX ? qtB : qtA;
#pragma unroll
            for (int d = 0; d < 16; ++d) {
                float v = ctx[d];
                v += __shfl_xor(v, 1);
                v += __shfl_xor(v, 2);
                v += __shfl_xor(v, 4);
                if (kl == 0)
                    atomicAdd(&out[(((size_t)b * 8 + h) * 512 + pqt * 32 + q) * 16 + d], v);
                ctx[d] = 0.f;
            }
            curX = X;
        }

        __syncthreads();
        int o_k = h * 16 + kt;
        for (int e = tid; e < NKv * 128; e += 256) {
            int g = e >> 7, c = e & 127;
            float4 v = *(const float4*)(Y + (((size_t)(NKv + g) * 2 + b) * 65536) +
                                        (size_t)o_k * 512 + c * 4);
            float bb = bconv[g * 128 + o_k];
            int kk = c >> 2, dd = (c & 3) * 4;
            float* kr = &Ks[g * 544 + kk * 17 + dd];
            kr[0] = v.x + bb; kr[1] = v.y + bb; kr[2] = v.z + bb; kr[3] = v.w + bb;
        }
        __syncthreads();

        int qg = qt * 32 + q;
        bool dg = (kt == qt);
        const float* Qrow = &Qs[X][q * 17];

        for (int ki = 0; ki < 4; ++ki) {
            int k_local = ki * 8 + kl;
            int kg = kt * 32 + k_local;
            float s[NKv];
#pragma unroll
            for (int g = 0; g < NKv; ++g) {
                const float* Kr = &Ks[g * 544 + k_local * 17];
                float a = 0.f;
#pragma unroll
                for (int d = 0; d < 16; ++d)
                    a = fmaf(Qrow[g * 544 + d], Kr[d], a);
                s[g] = a * 0.25f;
            }
            float m = s[0];
#pragma unroll
            for (int g = 1; g < NKv; ++g) m = fmaxf(m, s[g]);
            float wv2[NKv];
            float sum = 0.f;
#pragma unroll
            for (int g = 0; g < NKv; ++g) { wv2[g] = __expf(s[g] - m); sum += wv2[g]; }
            // masked (k>q) lanes in diagonal tile contribute ZERO here:
            // their uniform-0.1 term was already written by suffix_ctx.
            float inv = (dg && kg > qg) ? 0.f : (1.f / sum);
#pragma unroll
            for (int g = 0; g < NKv; ++g) {
                float wg = wv2[g] * inv;
                const float* Kr = &Ks[g * 544 + k_local * 17];
#pragma unroll
                for (int d = 0; d < 16; ++d)
                    ctx[d] = fmaf(wg, Kr[d], ctx[d]);
            }
        }
    }

    int pqt = curX ? qtB : qtA;
#pragma unroll
    for (int d = 0; d < 16; ++d) {
        float v = ctx[d];
        v += __shfl_xor(v, 1);
        v += __shfl_xor(v, 2);
        v += __shfl_xor(v, 4);
        if (kl == 0)
            atomicAdd(&out[(((size_t)b * 8 + h) * 512 + pqt * 32 + q) * 16 + d], v);
    }
}

// ---------------------------------------------------------------------------
extern "C" void kernel_launch(void* const* d_in, const int* in_sizes, int n_in,
                              void* d_out, int out_size, void* d_ws, size_t ws_size,
                              hipStream_t stream) {
    const float* Q = (const float*)d_in[0];
    const float* K = (const float*)d_in[1];
    const float* W = (const float*)d_in[3];
    const float* bconv = (const float*)d_in[4];
    float* out = (float*)d_out;

    float* Y = (float*)d_ws;
    unsigned short* xr = (unsigned short*)((char*)d_ws + XR_OFF);
    unsigned short* wb = (unsigned short*)((char*)d_ws + WB_OFF);

    zero_y<<<2048, 256, 0, stream>>>((float4*)Y, Y_BYTES / 16);

    int ctx_elems = Bv * Hv * Lv * DKv;              // 131072
    fill_ones4<<<2048, 256, 0, stream>>>((float4*)(out + ctx_elems),
                                         (out_size - ctx_elems) / 4);

    repack_x<<<256, 256, 0, stream>>>(Q, K, xr);
    repack_w<<<73 * 128, 256, 0, stream>>>(W, wb);

    conv_mfma<<<640, 512, 0, stream>>>(xr, wb, Y);

    suffix_ctx<<<16, 512, 0, stream>>>(Y, bconv, out);

    attn_phase2<<<256, 256, 0, stream>>>(Y, bconv, out);
}

// Round 7
// 268.124 us; speedup vs baseline: 1.5745x; 1.5745x over previous
//
#include <hip/hip_runtime.h>

// Problem constants
#define Bv 2
#define Hv 8
#define Lv 512
#define DKv 16
#define DMv 128          // H*DK
#define NKv 10
#define KSv 513

typedef __attribute__((ext_vector_type(8))) short short8;
typedef __attribute__((ext_vector_type(4))) float f32x4;

// chunk tables: nc_g = ceil((2^g+1)/16); chunks aligned to the END of the kernel
__device__ __constant__ int d_nc[10]     = {1,1,1,1,2,3,5,9,17,33};
__device__ __constant__ int d_cumnc[10]  = {0,1,2,3,4,6,9,14,23,40};
// total chunks = 73

// ws layout (bytes):
//   Y  : f32 [2 p][10 g][2 b][128 o][512 t]            = 10,485,760 B
//   xr : bf16 [2 p][2 b][512 t][128 i]                 =    524,288 B
//   Wb : bf16 [g][Tlocal][o][swz16(i)] packed          = 38,273,024 B
#define Y_BYTES   (10485760)
#define XR_OFF    (Y_BYTES)
#define WB_OFF    (Y_BYTES + 524288)

__device__ inline unsigned short f2bf(float f) {
    unsigned u = __float_as_uint(f);
    unsigned r = (u + 0x7FFFu + ((u >> 16) & 1u)) >> 16;
    return (unsigned short)r;
}

// async global->LDS 16B per lane; lds dest wave-uniform (lane*16 added by HW)
__device__ __forceinline__ void gld_lds16(const void* g, void* l) {
    __builtin_amdgcn_global_load_lds(
        (const __attribute__((address_space(1))) unsigned int*)g,
        (__attribute__((address_space(3))) unsigned int*)l,
        16, 0, 0);
}

// stage one 32KB tap plane (16384 ushorts): 8 waves x 4 segs x (64 lanes*16B)
__device__ __forceinline__ void stage_plane(const unsigned short* __restrict__ g,
                                            unsigned short* l, int wv, int ln) {
#pragma unroll
    for (int k = 0; k < 4; ++k) {
        int seg = k * 8 + wv;                       // 32 segs of 512 ushorts
        gld_lds16(g + seg * 512 + ln * 8, l + seg * 512);
    }
}

// ---------------------------------------------------------------------------
__global__ void zero_y(float4* __restrict__ p, int n4) {
    int stride = gridDim.x * 256;
    for (int i = blockIdx.x * 256 + threadIdx.x; i < n4; i += stride)
        p[i] = make_float4(0.f, 0.f, 0.f, 0.f);
}

// attn_out region = 1.0 (softmax over g sums to 1, even for masked entries)
__global__ void fill_ones4(float4* __restrict__ p, int n4) {
    int stride = gridDim.x * 256;
    for (int i = blockIdx.x * 256 + threadIdx.x; i < n4; i += stride)
        p[i] = make_float4(1.f, 1.f, 1.f, 1.f);
}

// ---------------------------------------------------------------------------
// xr[p][b][t][i] = bf16( flat reinterpret of Q/K [B,H,L,DK] -> [B, L, DM] )
__global__ void repack_x(const float* __restrict__ Q, const float* __restrict__ K,
                         unsigned short* __restrict__ xr) {
    int idx = blockIdx.x * 256 + threadIdx.x;        // 65536 items of 4 elems
    if (idx >= 65536) return;
    int flat = idx * 4;
    int p = flat >> 17;
    int off = flat & 131071;
    const float* src = p ? K : Q;
    float4 v = *(const float4*)(src + off);
    ushort4 o;
    o.x = f2bf(v.x); o.y = f2bf(v.y); o.z = f2bf(v.z); o.w = f2bf(v.w);
    *(ushort4*)(xr + flat) = o;
}

// ---------------------------------------------------------------------------
// Wb[g][Tlocal][o][swz(i)] <- W[g][o*128+i][513 - w_g + Tlocal], 0 if col<0.
// i stored at slot (i>>3)^(o&15): conv's LDS A-reads become conflict-free
// (each 16-lane group reads 16 distinct 16B slots). DMA copies linearly so
// LDS inherits this layout (swizzle-the-source pattern).
__global__ __launch_bounds__(256) void repack_w(const float* __restrict__ W,
                                                unsigned short* __restrict__ wb) {
    int bid = blockIdx.x;
    int cid = bid >> 7;
    int o = bid & 127;                   // one output channel per block
    int g, rem = cid;
#pragma unroll
    for (g = 0; g < 10; ++g) { int nc = d_nc[g]; if (rem < nc) break; rem -= nc; }
    int cl = rem;
    int w_g = d_nc[g] * 16;
    int ccol = w_g - 16 * (cl + 1);
    int wcolbase = 513 - w_g + ccol;      // absolute W col of this chunk's tap 0

    __shared__ float tile[128][17];
    const float* wsrc = W + (size_t)g * 16384 * 513 + (size_t)o * 128 * 513;
    int tid = threadIdx.x;
    int rr = tid >> 4, cc = tid & 15;
    int col = wcolbase + cc;
    for (int r = rr; r < 128; r += 16) {          // r = i
        float v = 0.f;
        if (col >= 0) v = wsrc[(size_t)r * 513 + col];
        tile[r][cc] = v;
    }
    __syncthreads();
    unsigned short* wdst = wb + (size_t)262144 * d_cumnc[g];
    int i = tid & 127, ccw = tid >> 7;
    int iswz = (((i >> 3) ^ (o & 15)) << 3) | (i & 7);
    for (int c2 = ccw; c2 < 16; c2 += 2) {
        wdst[(size_t)(ccol + c2) * 16384 + o * 128 + iswz] = f2bf(tile[i][c2]);
    }
}

// ---------------------------------------------------------------------------
// conv via MFMA. A-plane (32KB/tap) double-buffered in LDS via global_load_lds,
// counted vmcnt(4) (never drained mid-loop), raw barriers. B window in LDS
// with slot-rotation swizzle. 1-D grid 640: j -> r=j&7 (XCD), yy=(j>>3)&7,
// cid=(j>>6)*8+r -> the 8 yy-siblings of a cid share one XCD (L2-resident A).
__global__ __launch_bounds__(512) void conv_mfma(const unsigned short* __restrict__ xr,
                                                 const unsigned short* __restrict__ wb,
                                                 float* __restrict__ Y) {
    int j = blockIdx.x;
    int r = j & 7, yy = (j >> 3) & 7, qq = j >> 6;
    int cid = qq * 8 + r;
    if (cid >= 73) return;
    int g, rem = cid;
#pragma unroll
    for (g = 0; g < 10; ++g) { int nc = d_nc[g]; if (rem < nc) break; rem -= nc; }
    int cl = rem;
    int w_g = d_nc[g] * 16;
    int ccol = w_g - 16 * (cl + 1);

    int p = yy >> 2, b = (yy >> 1) & 1, tt = yy & 1;
    int t0 = tt * 256;
    int pb = yy >> 1;

    int xbase = t0 + 1 - 16 * (cl + 1);    // x index of xs row 0
    if (xbase < -270) return;              // window entirely before t=0 -> zeros

    // xs[u][slot]: element (u,i) at u*136 + ((i>>3 + u)&15)*8 + (i&7)
    __shared__ unsigned short xs[272 * 136];
    __shared__ unsigned short As[2][16384];      // double-buffered tap plane

    int tid = threadIdx.x;
    int wv = tid >> 6, ln = tid & 63;
    int lane = ln;
    int wm = wv >> 2, wn = wv & 3;
    int l15 = lane & 15, q = lane >> 4;

    const unsigned short* wgp = wb + (size_t)262144 * d_cumnc[g] + (size_t)ccol * 16384;

    // prologue: issue plane 0 + 1 DMA, stage xs, one full drain
    stage_plane(wgp, As[0], wv, ln);
    stage_plane(wgp + 16384, As[1], wv, ln);

    const unsigned short* xp = xr + (size_t)pb * 65536;
    for (int e = tid; e < 272 * 16; e += 512) {
        int u = e >> 4, ic = e & 15;
        int xi = xbase + u;
        short8 v = (short8)0;
        if (xi >= 0 && xi < 512) v = *(const short8*)(xp + (size_t)xi * 128 + ic * 8);
        *(short8*)(&xs[u * 136 + ((ic + u) & 15) * 8]) = v;
    }
    __syncthreads();                        // planes 0,1 + xs all resident

    f32x4 acc[4][4];
#pragma unroll
    for (int mt = 0; mt < 4; ++mt)
#pragma unroll
        for (int nt = 0; nt < 4; ++nt) acc[mt][nt] = (f32x4)0.f;

    // per-lane A-slot offsets: slot = (ib*4+q) ^ l15 (conflict-free per 16-lane grp)
    int aslot[4];
#pragma unroll
    for (int ib = 0; ib < 4; ++ib) aslot[ib] = (((ib * 4 + q) ^ l15) << 3);

    for (int jj = 0; jj < 16; ++jj) {
        const unsigned short* Ac = As[jj & 1];
        int row0 = wn * 64 + l15 + jj;
#pragma unroll
        for (int ib = 0; ib < 4; ++ib) {
            short8 a[4], bq[4];
#pragma unroll
            for (int mt = 0; mt < 4; ++mt)
                a[mt] = *(const short8*)(&Ac[(wm * 64 + mt * 16 + l15) * 128 + aslot[ib]]);
#pragma unroll
            for (int nt = 0; nt < 4; ++nt) {
                int row = row0 + nt * 16;
                bq[nt] = *(const short8*)(&xs[row * 136 + ((ib * 4 + q + row) & 15) * 8]);
            }
#pragma unroll
            for (int mt = 0; mt < 4; ++mt)
#pragma unroll
                for (int nt = 0; nt < 4; ++nt)
                    acc[mt][nt] = __builtin_amdgcn_mfma_f32_16x16x32_bf16(
                        a[mt], bq[nt], acc[mt][nt], 0, 0, 0);
        }
        if (jj == 15) break;

        __builtin_amdgcn_sched_barrier(0);
        __builtin_amdgcn_s_barrier();             // all waves done reading As[jj&1]
        if (jj + 2 < 16)
            stage_plane(wgp + (size_t)(jj + 2) * 16384, As[jj & 1], wv, ln);
        if (jj < 14)
            asm volatile("s_waitcnt vmcnt(4)" ::: "memory");   // plane jj+1 arrived
        else
            asm volatile("s_waitcnt vmcnt(0)" ::: "memory");
        __builtin_amdgcn_s_barrier();
        __builtin_amdgcn_sched_barrier(0);
    }

    // epilogue: atomic accumulate into Y[p][g][b][o][t]
    float* yp = Y + (((size_t)p * NKv + g) * 2 + b) * 65536;
    int orow = wm * 64 + q * 4;
    int tcol = t0 + wn * 64 + l15;
#pragma unroll
    for (int mt = 0; mt < 4; ++mt)
#pragma unroll
        for (int nt = 0; nt < 4; ++nt)
#pragma unroll
            for (int rr = 0; rr < 4; ++rr)
                atomicAdd(&yp[(size_t)(orow + mt * 16 + rr) * 512 + tcol + nt * 16],
                          acc[mt][nt][rr]);
}

// ---------------------------------------------------------------------------
// Masked-entry context: for masked (q,k) the scale-softmax is uniform 0.1,
// so ctx_masked[q,d] = 0.1 * sum_{k>q} S[k,d], S[k,d] = sum_g (K_p + bias).
// WRITES the out ctx region (attn_phase2 then atomicAdds unmasked parts).
__global__ __launch_bounds__(512) void suffix_ctx(const float* __restrict__ Y,
                                                  const float* __restrict__ bconv,
                                                  float* __restrict__ out) {
    int bh = blockIdx.x;        // 16
    int b = bh >> 3, h = bh & 7;
    int tid = threadIdx.x;
    int d = tid & 15;
    int s = tid >> 4;           // stripe 0..31, k in [s*16, s*16+16)

    __shared__ float tot[32][17];
    float S[16];
#pragma unroll
    for (int j = 0; j < 16; ++j) {
        int k = s * 16 + j;
        int o = h * 16 + (k >> 5);
        int t = (k & 31) * 16 + d;
        float acc = 0.f;
#pragma unroll
        for (int g = 0; g < NKv; ++g)
            acc += Y[(((size_t)(NKv + g) * 2 + b) * 65536) + (size_t)o * 512 + t]
                 + bconv[g * 128 + o];
        S[j] = acc;
    }
    float mytot = 0.f;
#pragma unroll
    for (int j = 0; j < 16; ++j) mytot += S[j];
    tot[s][d] = mytot;
    __syncthreads();
    float run = 0.f;
    for (int s2 = s + 1; s2 < 32; ++s2) run += tot[s2][d];
#pragma unroll
    for (int j = 15; j >= 0; --j) {
        int qv = s * 16 + j;
        out[(((size_t)b * 8 + h) * 512 + qv) * 16 + d] = 0.1f * run;
        run += S[j];
    }
}

// ---------------------------------------------------------------------------
// phase 2: unmasked (k<=q) part, ONLINE softmax over g (single pass over K,
// PV fused). float4 LDS reads, rows padded to stride 20 (16B-aligned).
__global__ __launch_bounds__(256) void attn_phase2(const float* __restrict__ Y,
                                                   const float* __restrict__ bconv,
                                                   float* __restrict__ out) {
    int blk = blockIdx.x;          // 256
    int half = blk & 1;
    int pr = blk >> 1;             // 128 pairs
    int bh = pr >> 3;
    int qp = pr & 7;
    int b = bh >> 3, h = bh & 7;

    int qtA = qp, qtB = 15 - qp;
    int u0 = half ? 8 : 0, u1 = half ? 17 : 8;

    __shared__ float Qs[2][NKv * 640];   // [X][g*640 + q*20 + d]
    __shared__ float Ks[NKv * 640];

    int tid = threadIdx.x;

#pragma unroll
    for (int X = 0; X < 2; ++X) {
        int o = h * 16 + (X ? qtB : qtA);
        for (int e = tid; e < NKv * 128; e += 256) {
            int g = e >> 7, c = e & 127;
            float4 v = *(const float4*)(Y + (((size_t)g * 2 + b) * 65536) +
                                        (size_t)o * 512 + c * 4);
            float bb = bconv[g * 128 + o];
            int qq2 = c >> 2, dd = c & 3;
            *(float4*)&Qs[X][g * 640 + qq2 * 20 + dd * 4] =
                make_float4(v.x + bb, v.y + bb, v.z + bb, v.w + bb);
        }
    }

    int q = tid >> 3;    // 0..31
    int kl = tid & 7;    // 0..7
    float ctx[16];
#pragma unroll
    for (int d = 0; d < 16; ++d) ctx[d] = 0.f;
    int curX = (u0 <= qtA) ? 0 : 1;

    for (int u = u0; u < u1; ++u) {
        int X = (u <= qtA) ? 0 : 1;
        int qt = X ? qtB : qtA;
        int kt = X ? (u - qtA - 1) : u;

        if (X != curX) {
            int pqt = curX ? qtB : qtA;
#pragma unroll
            for (int d = 0; d < 16; ++d) {
                float v = ctx[d];
                v += __shfl_xor(v, 1);
                v += __shfl_xor(v, 2);
                v += __shfl_xor(v, 4);
                if (kl == 0)
                    atomicAdd(&out[(((size_t)b * 8 + h) * 512 + pqt * 32 + q) * 16 + d], v);
                ctx[d] = 0.f;
            }
            curX = X;
        }

        __syncthreads();
        int o_k = h * 16 + kt;
        for (int e = tid; e < NKv * 128; e += 256) {
            int g = e >> 7, c = e & 127;
            float4 v = *(const float4*)(Y + (((size_t)(NKv + g) * 2 + b) * 65536) +
                                        (size_t)o_k * 512 + c * 4);
            float bb = bconv[g * 128 + o_k];
            int kk = c >> 2, dd = c & 3;
            *(float4*)&Ks[g * 640 + kk * 20 + dd * 4] =
                make_float4(v.x + bb, v.y + bb, v.z + bb, v.w + bb);
        }
        __syncthreads();

        int qg = qt * 32 + q;
        bool dg = (kt == qt);

        float m[4] = {-1e30f, -1e30f, -1e30f, -1e30f};
        float l[4] = {0.f, 0.f, 0.f, 0.f};
        float ca[4][16];
#pragma unroll
        for (int ki = 0; ki < 4; ++ki)
#pragma unroll
            for (int d = 0; d < 16; ++d) ca[ki][d] = 0.f;

        for (int g = 0; g < NKv; ++g) {
            const float* Qg = &Qs[X][g * 640 + q * 20];
            float4 qv0 = *(const float4*)(Qg);
            float4 qv1 = *(const float4*)(Qg + 4);
            float4 qv2 = *(const float4*)(Qg + 8);
            float4 qv3 = *(const float4*)(Qg + 12);
#pragma unroll
            for (int ki = 0; ki < 4; ++ki) {
                const float* Kg = &Ks[g * 640 + (ki * 8 + kl) * 20];
                float kv[16];
                *(float4*)&kv[0]  = *(const float4*)(Kg);
                *(float4*)&kv[4]  = *(const float4*)(Kg + 4);
                *(float4*)&kv[8]  = *(const float4*)(Kg + 8);
                *(float4*)&kv[12] = *(const float4*)(Kg + 12);
                float s = 0.f;
                s = fmaf(qv0.x, kv[0], s);  s = fmaf(qv0.y, kv[1], s);
                s = fmaf(qv0.z, kv[2], s);  s = fmaf(qv0.w, kv[3], s);
                s = fmaf(qv1.x, kv[4], s);  s = fmaf(qv1.y, kv[5], s);
                s = fmaf(qv1.z, kv[6], s);  s = fmaf(qv1.w, kv[7], s);
                s = fmaf(qv2.x, kv[8], s);  s = fmaf(qv2.y, kv[9], s);
                s = fmaf(qv2.z, kv[10], s); s = fmaf(qv2.w, kv[11], s);
                s = fmaf(qv3.x, kv[12], s); s = fmaf(qv3.y, kv[13], s);
                s = fmaf(qv3.z, kv[14], s); s = fmaf(qv3.w, kv[15], s);
                s *= 0.25f;
                float mn = fmaxf(m[ki], s);
                float sc = __expf(m[ki] - mn);
                float w  = __expf(s - mn);
                m[ki] = mn;
                l[ki] = l[ki] * sc + w;
#pragma unroll
                for (int d = 0; d < 16; ++d)
                    ca[ki][d] = fmaf(ca[ki][d], sc, w * kv[d]);
            }
        }

        // merge per-ki accumulators (masked diag lanes contribute 0; their
        // uniform-0.1 part was written by suffix_ctx)
#pragma unroll
        for (int ki = 0; ki < 4; ++ki) {
            int kg = kt * 32 + ki * 8 + kl;
            float inv = (dg && kg > qg) ? 0.f : (1.f / l[ki]);
#pragma unroll
            for (int d = 0; d < 16; ++d) ctx[d] = fmaf(ca[ki][d], inv, ctx[d]);
        }
    }

    int pqt = curX ? qtB : qtA;
#pragma unroll
    for (int d = 0; d < 16; ++d) {
        float v = ctx[d];
        v += __shfl_xor(v, 1);
        v += __shfl_xor(v, 2);
        v += __shfl_xor(v, 4);
        if (kl == 0)
            atomicAdd(&out[(((size_t)b * 8 + h) * 512 + pqt * 32 + q) * 16 + d], v);
    }
}

// ---------------------------------------------------------------------------
extern "C" void kernel_launch(void* const* d_in, const int* in_sizes, int n_in,
                              void* d_out, int out_size, void* d_ws, size_t ws_size,
                              hipStream_t stream) {
    const float* Q = (const float*)d_in[0];
    const float* K = (const float*)d_in[1];
    const float* W = (const float*)d_in[3];
    const float* bconv = (const float*)d_in[4];
    float* out = (float*)d_out;

    float* Y = (float*)d_ws;
    unsigned short* xr = (unsigned short*)((char*)d_ws + XR_OFF);
    unsigned short* wb = (unsigned short*)((char*)d_ws + WB_OFF);

    zero_y<<<2048, 256, 0, stream>>>((float4*)Y, Y_BYTES / 16);

    int ctx_elems = Bv * Hv * Lv * DKv;              // 131072
    fill_ones4<<<2048, 256, 0, stream>>>((float4*)(out + ctx_elems),
                                         (out_size - ctx_elems) / 4);

    repack_x<<<256, 256, 0, stream>>>(Q, K, xr);
    repack_w<<<73 * 128, 256, 0, stream>>>(W, wb);

    conv_mfma<<<640, 512, 0, stream>>>(xr, wb, Y);

    suffix_ctx<<<16, 512, 0, stream>>>(Y, bconv, out);

    attn_phase2<<<256, 256, 0, stream>>>(Y, bconv, out);
}

// Round 8
// 253.440 us; speedup vs baseline: 1.6658x; 1.0579x over previous
//
#include <hip/hip_runtime.h>

// Problem constants
#define Bv 2
#define Hv 8
#define Lv 512
#define DKv 16
#define DMv 128          // H*DK
#define NKv 10
#define KSv 513

typedef __attribute__((ext_vector_type(8))) short short8;
typedef __attribute__((ext_vector_type(4))) float f32x4;

// chunk tables: nc_g = ceil((2^g+1)/16); chunks aligned to the END of the kernel
__device__ __constant__ int d_nc[10]     = {1,1,1,1,2,3,5,9,17,33};
__device__ __constant__ int d_cumnc[10]  = {0,1,2,3,4,6,9,14,23,40};
// total chunks = 73

// ws layout (bytes):
//   Y  : f32 [2 p][10 g][2 b][128 o][512 t]            = 10,485,760 B
//   xr : bf16 [2 p][2 b][512 t][128 i]                 =    524,288 B
//   Wb : bf16 [g][Tlocal][ A-frag layout ]             = 38,273,024 B
//        plane off(o,i) = ((o>>4)*4 + (i>>5))*512 + (o&15)*32 + (i&31)
//        -> per (mt,ib) a wave's 64 lanes read ONE contiguous 1KB run
#define Y_BYTES   (10485760)
#define XR_OFF    (Y_BYTES)
#define WB_OFF    (Y_BYTES + 524288)

__device__ inline unsigned short f2bf(float f) {
    unsigned u = __float_as_uint(f);
    unsigned r = (u + 0x7FFFu + ((u >> 16) & 1u)) >> 16;
    return (unsigned short)r;
}

// ---------------------------------------------------------------------------
__global__ void zero_y(float4* __restrict__ p, int n4) {
    int stride = gridDim.x * 256;
    for (int i = blockIdx.x * 256 + threadIdx.x; i < n4; i += stride)
        p[i] = make_float4(0.f, 0.f, 0.f, 0.f);
}

// attn_out region = 1.0 (softmax over g sums to 1, even for masked entries)
__global__ void fill_ones4(float4* __restrict__ p, int n4) {
    int stride = gridDim.x * 256;
    for (int i = blockIdx.x * 256 + threadIdx.x; i < n4; i += stride)
        p[i] = make_float4(1.f, 1.f, 1.f, 1.f);
}

// ---------------------------------------------------------------------------
// xr[p][b][t][i] = bf16( flat reinterpret of Q/K [B,H,L,DK] -> [B, L, DM] )
__global__ void repack_x(const float* __restrict__ Q, const float* __restrict__ K,
                         unsigned short* __restrict__ xr) {
    int idx = blockIdx.x * 256 + threadIdx.x;        // 65536 items of 4 elems
    if (idx >= 65536) return;
    int flat = idx * 4;
    int p = flat >> 17;
    int off = flat & 131071;
    const float* src = p ? K : Q;
    float4 v = *(const float4*)(src + off);
    ushort4 o;
    o.x = f2bf(v.x); o.y = f2bf(v.y); o.z = f2bf(v.z); o.w = f2bf(v.w);
    *(ushort4*)(xr + flat) = o;
}

// ---------------------------------------------------------------------------
// Wb plane layout: off(o,i) = ((o>>4)*4 + (i>>5))*512 + (o&15)*32 + (i&31)
// One block per (chunk cid, o). Reads W[g][o*128+i][tapcol], writes 16 taps.
__global__ __launch_bounds__(256) void repack_w(const float* __restrict__ W,
                                                unsigned short* __restrict__ wb) {
    int bid = blockIdx.x;
    int cid = bid >> 7;
    int o = bid & 127;
    int g, rem = cid;
#pragma unroll
    for (g = 0; g < 10; ++g) { int nc = d_nc[g]; if (rem < nc) break; rem -= nc; }
    int cl = rem;
    int w_g = d_nc[g] * 16;
    int ccol = w_g - 16 * (cl + 1);
    int wcolbase = 513 - w_g + ccol;      // absolute W col of this chunk's tap 0

    __shared__ float tile[128][17];       // [i][tap]
    const float* wsrc = W + (size_t)g * 16384 * 513 + (size_t)o * 128 * 513;
    int tid = threadIdx.x;
    int rr = tid >> 4, cc = tid & 15;
    int col = wcolbase + cc;
    for (int r = rr; r < 128; r += 16) {          // r = i
        float v = 0.f;
        if (col >= 0) v = wsrc[(size_t)r * 513 + col];
        tile[r][cc] = v;
    }
    __syncthreads();

    unsigned short* wdst = wb + (size_t)262144 * d_cumnc[g];
    int c2 = tid >> 4;          // tap 0..15
    int s  = tid & 15;          // ib(2) | qv(2)
    int ib = s >> 2, qv = s & 3;
    int i0 = ib * 32 + qv * 8;
    unsigned short pack[8];
#pragma unroll
    for (int e = 0; e < 8; ++e) pack[e] = f2bf(tile[i0 + e][c2]);
    size_t off = (size_t)(ccol + c2) * 16384 +
                 (((o >> 4) * 4 + ib) * 512 + (o & 15) * 32 + qv * 8);
    *(short8*)(wdst + off) = *(short8*)pack;      // 16B contiguous per thread
}

// ---------------------------------------------------------------------------
// conv v5: A-frags streamed L2->registers (coalesced 1KB wave-loads, no LDS
// staging, no inner barriers). B (x window) in LDS, rotation-swizzled.
// Tile M=128 o x N=128 t, 4 waves (2 wm x 2 wn). Grid 1280: j -> r=j&7 (XCD),
// yy=(j>>3)&15 (pb*4+tt), cid=(j>>7)*8+r -> 16 siblings share an XCD's L2.
__global__ __launch_bounds__(256, 3) void conv_mfma(const unsigned short* __restrict__ xr,
                                                    const unsigned short* __restrict__ wb,
                                                    float* __restrict__ Y) {
    int j = blockIdx.x;
    int r = j & 7, yy = (j >> 3) & 15, qq = j >> 7;
    int cid = qq * 8 + r;
    if (cid >= 73) return;
    int g, rem = cid;
#pragma unroll
    for (g = 0; g < 10; ++g) { int nc = d_nc[g]; if (rem < nc) break; rem -= nc; }
    int cl = rem;
    int w_g = d_nc[g] * 16;
    int ccol = w_g - 16 * (cl + 1);

    int pb = yy >> 2;                      // p*2+b
    int p = pb >> 1, b = pb & 1;
    int tt = yy & 3;
    int t0 = tt * 128;

    int xbase = t0 + 1 - 16 * (cl + 1);    // x index of xs row 0
    if (xbase < -142) return;              // window [xbase, xbase+142] all < 0

    // xs: element (u,i) at u*128 + (((i>>3)+u)&15)*8 + (i&7)
    __shared__ unsigned short xs[143 * 128];

    int tid = threadIdx.x;
    const unsigned short* xp = xr + (size_t)pb * 65536;
    for (int e = tid; e < 143 * 16; e += 256) {
        int u = e >> 4, ic = e & 15;
        int xi = xbase + u;
        short8 v = (short8)0;
        if (xi >= 0 && xi < 512) v = *(const short8*)(xp + (size_t)xi * 128 + ic * 8);
        *(short8*)(&xs[u * 128 + (((ic + u) & 15) << 3)]) = v;
    }
    __syncthreads();                        // only barrier in the kernel

    int lane = tid & 63, wv = tid >> 6;     // 4 waves: 2 wm x 2 wn
    int wm = wv >> 1, wn = wv & 1;
    int l15 = lane & 15, q = lane >> 4;

    const unsigned short* wgp = wb + (size_t)262144 * d_cumnc[g] + (size_t)ccol * 16384;
    int abase = l15 * 32 + q * 8;

    f32x4 acc[4][4];
#pragma unroll
    for (int mt = 0; mt < 4; ++mt)
#pragma unroll
        for (int nt = 0; nt < 4; ++nt) acc[mt][nt] = (f32x4)0.f;

    for (int jj = 0; jj < 16; ++jj) {
        const unsigned short* tp = wgp + (size_t)jj * 16384;
        int row0 = wn * 64 + l15 + jj;
#pragma unroll
        for (int ib = 0; ib < 4; ++ib) {
            short8 a[4], bq[4];
#pragma unroll
            for (int mt = 0; mt < 4; ++mt)
                a[mt] = *(const short8*)(tp + ((wm * 4 + mt) * 4 + ib) * 512 + abase);
#pragma unroll
            for (int nt = 0; nt < 4; ++nt) {
                int row = row0 + nt * 16;
                bq[nt] = *(const short8*)(&xs[row * 128 + (((ib * 4 + q + row) & 15) << 3)]);
            }
#pragma unroll
            for (int mt = 0; mt < 4; ++mt)
#pragma unroll
                for (int nt = 0; nt < 4; ++nt)
                    acc[mt][nt] = __builtin_amdgcn_mfma_f32_16x16x32_bf16(
                        a[mt], bq[nt], acc[mt][nt], 0, 0, 0);
        }
    }

    // epilogue: atomic accumulate into Y[p][g][b][o][t]
    float* yp = Y + (((size_t)p * NKv + g) * 2 + b) * 65536;
    int orow = wm * 64 + q * 4;
    int tcol = t0 + wn * 64 + l15;
#pragma unroll
    for (int mt = 0; mt < 4; ++mt)
#pragma unroll
        for (int nt = 0; nt < 4; ++nt)
#pragma unroll
            for (int rr = 0; rr < 4; ++rr)
                atomicAdd(&yp[(size_t)(orow + mt * 16 + rr) * 512 + tcol + nt * 16],
                          acc[mt][nt][rr]);
}

// ---------------------------------------------------------------------------
// Masked-entry context: ctx_masked[q,d] = 0.1 * sum_{k>q} S[k,d],
// S[k,d] = sum_g (K_p + bias). WRITES out ctx region.
__global__ __launch_bounds__(512) void suffix_ctx(const float* __restrict__ Y,
                                                  const float* __restrict__ bconv,
                                                  float* __restrict__ out) {
    int bh = blockIdx.x;        // 16
    int b = bh >> 3, h = bh & 7;
    int tid = threadIdx.x;
    int d = tid & 15;
    int s = tid >> 4;           // stripe 0..31, k in [s*16, s*16+16)

    __shared__ float tot[32][17];
    float S[16];
#pragma unroll
    for (int jv = 0; jv < 16; ++jv) {
        int k = s * 16 + jv;
        int o = h * 16 + (k >> 5);
        int t = (k & 31) * 16 + d;
        float acc = 0.f;
#pragma unroll
        for (int g = 0; g < NKv; ++g)
            acc += Y[(((size_t)(NKv + g) * 2 + b) * 65536) + (size_t)o * 512 + t]
                 + bconv[g * 128 + o];
        S[jv] = acc;
    }
    float mytot = 0.f;
#pragma unroll
    for (int jv = 0; jv < 16; ++jv) mytot += S[jv];
    tot[s][d] = mytot;
    __syncthreads();
    float run = 0.f;
    for (int s2 = s + 1; s2 < 32; ++s2) run += tot[s2][d];
#pragma unroll
    for (int jv = 15; jv >= 0; --jv) {
        int qv = s * 16 + jv;
        out[(((size_t)b * 8 + h) * 512 + qv) * 16 + d] = 0.1f * run;
        run += S[jv];
    }
}

// ---------------------------------------------------------------------------
// phase 2: unmasked (k<=q) part, online softmax over g, 512 threads
// (32 q x 16 kl, 2 ki) -> 2 waves/SIMD.
__global__ __launch_bounds__(512) void attn_phase2(const float* __restrict__ Y,
                                                   const float* __restrict__ bconv,
                                                   float* __restrict__ out) {
    int blk = blockIdx.x;          // 256
    int half = blk & 1;
    int pr = blk >> 1;             // 128 pairs
    int bh = pr >> 3;
    int qp = pr & 7;
    int b = bh >> 3, h = bh & 7;

    int qtA = qp, qtB = 15 - qp;
    int u0 = half ? 8 : 0, u1 = half ? 17 : 8;

    __shared__ float Qs[2][NKv * 640];   // [X][g*640 + q*20 + d]
    __shared__ float Ks[NKv * 640];

    int tid = threadIdx.x;

#pragma unroll
    for (int X = 0; X < 2; ++X) {
        int o = h * 16 + (X ? qtB : qtA);
        for (int e = tid; e < NKv * 128; e += 512) {
            int g = e >> 7, c = e & 127;
            float4 v = *(const float4*)(Y + (((size_t)g * 2 + b) * 65536) +
                                        (size_t)o * 512 + c * 4);
            float bb = bconv[g * 128 + o];
            int qq2 = c >> 2, dd = c & 3;
            *(float4*)&Qs[X][g * 640 + qq2 * 20 + dd * 4] =
                make_float4(v.x + bb, v.y + bb, v.z + bb, v.w + bb);
        }
    }

    int q = (tid >> 4) & 31;
    int kl = tid & 15;
    float ctx[16];
#pragma unroll
    for (int d = 0; d < 16; ++d) ctx[d] = 0.f;
    int curX = (u0 <= qtA) ? 0 : 1;

    for (int u = u0; u < u1; ++u) {
        int X = (u <= qtA) ? 0 : 1;
        int qt = X ? qtB : qtA;
        int kt = X ? (u - qtA - 1) : u;

        if (X != curX) {
            int pqt = curX ? qtB : qtA;
#pragma unroll
            for (int d = 0; d < 16; ++d) {
                float v = ctx[d];
                v += __shfl_xor(v, 1);
                v += __shfl_xor(v, 2);
                v += __shfl_xor(v, 4);
                v += __shfl_xor(v, 8);
                if (kl == 0)
                    atomicAdd(&out[(((size_t)b * 8 + h) * 512 + pqt * 32 + q) * 16 + d], v);
                ctx[d] = 0.f;
            }
            curX = X;
        }

        __syncthreads();
        int o_k = h * 16 + kt;
        for (int e = tid; e < NKv * 128; e += 512) {
            int g = e >> 7, c = e & 127;
            float4 v = *(const float4*)(Y + (((size_t)(NKv + g) * 2 + b) * 65536) +
                                        (size_t)o_k * 512 + c * 4);
            float bb = bconv[g * 128 + o_k];
            int kk = c >> 2, dd = c & 3;
            *(float4*)&Ks[g * 640 + kk * 20 + dd * 4] =
                make_float4(v.x + bb, v.y + bb, v.z + bb, v.w + bb);
        }
        __syncthreads();

        int qg = qt * 32 + q;
        bool dg = (kt == qt);

        float m[2] = {-1e30f, -1e30f};
        float l[2] = {0.f, 0.f};
        float ca[2][16];
#pragma unroll
        for (int ki = 0; ki < 2; ++ki)
#pragma unroll
            for (int d = 0; d < 16; ++d) ca[ki][d] = 0.f;

        for (int g = 0; g < NKv; ++g) {
            const float* Qg = &Qs[X][g * 640 + q * 20];
            float4 qv0 = *(const float4*)(Qg);
            float4 qv1 = *(const float4*)(Qg + 4);
            float4 qv2 = *(const float4*)(Qg + 8);
            float4 qv3 = *(const float4*)(Qg + 12);
#pragma unroll
            for (int ki = 0; ki < 2; ++ki) {
                const float* Kg = &Ks[g * 640 + (ki * 16 + kl) * 20];
                float kv[16];
                *(float4*)&kv[0]  = *(const float4*)(Kg);
                *(float4*)&kv[4]  = *(const float4*)(Kg + 4);
                *(float4*)&kv[8]  = *(const float4*)(Kg + 8);
                *(float4*)&kv[12] = *(const float4*)(Kg + 12);
                float s = 0.f;
                s = fmaf(qv0.x, kv[0], s);  s = fmaf(qv0.y, kv[1], s);
                s = fmaf(qv0.z, kv[2], s);  s = fmaf(qv0.w, kv[3], s);
                s = fmaf(qv1.x, kv[4], s);  s = fmaf(qv1.y, kv[5], s);
                s = fmaf(qv1.z, kv[6], s);  s = fmaf(qv1.w, kv[7], s);
                s = fmaf(qv2.x, kv[8], s);  s = fmaf(qv2.y, kv[9], s);
                s = fmaf(qv2.z, kv[10], s); s = fmaf(qv2.w, kv[11], s);
                s = fmaf(qv3.x, kv[12], s); s = fmaf(qv3.y, kv[13], s);
                s = fmaf(qv3.z, kv[14], s); s = fmaf(qv3.w, kv[15], s);
                s *= 0.25f;
                float mn = fmaxf(m[ki], s);
                float sc = __expf(m[ki] - mn);
                float w  = __expf(s - mn);
                m[ki] = mn;
                l[ki] = l[ki] * sc + w;
#pragma unroll
                for (int d = 0; d < 16; ++d)
                    ca[ki][d] = fmaf(ca[ki][d], sc, w * kv[d]);
            }
        }

#pragma unroll
        for (int ki = 0; ki < 2; ++ki) {
            int kg = kt * 32 + ki * 16 + kl;
            float inv = (dg && kg > qg) ? 0.f : (1.f / l[ki]);
#pragma unroll
            for (int d = 0; d < 16; ++d) ctx[d] = fmaf(ca[ki][d], inv, ctx[d]);
        }
    }

    int pqt = curX ? qtB : qtA;
#pragma unroll
    for (int d = 0; d < 16; ++d) {
        float v = ctx[d];
        v += __shfl_xor(v, 1);
        v += __shfl_xor(v, 2);
        v += __shfl_xor(v, 4);
        v += __shfl_xor(v, 8);
        if (kl == 0)
            atomicAdd(&out[(((size_t)b * 8 + h) * 512 + pqt * 32 + q) * 16 + d], v);
    }
}

// ---------------------------------------------------------------------------
extern "C" void kernel_launch(void* const* d_in, const int* in_sizes, int n_in,
                              void* d_out, int out_size, void* d_ws, size_t ws_size,
                              hipStream_t stream) {
    const float* Q = (const float*)d_in[0];
    const float* K = (const float*)d_in[1];
    const float* W = (const float*)d_in[3];
    const float* bconv = (const float*)d_in[4];
    float* out = (float*)d_out;

    float* Y = (float*)d_ws;
    unsigned short* xr = (unsigned short*)((char*)d_ws + XR_OFF);
    unsigned short* wb = (unsigned short*)((char*)d_ws + WB_OFF);

    zero_y<<<2048, 256, 0, stream>>>((float4*)Y, Y_BYTES / 16);

    int ctx_elems = Bv * Hv * Lv * DKv;              // 131072
    fill_ones4<<<2048, 256, 0, stream>>>((float4*)(out + ctx_elems),
                                         (out_size - ctx_elems) / 4);

    repack_x<<<256, 256, 0, stream>>>(Q, K, xr);
    repack_w<<<73 * 128, 256, 0, stream>>>(W, wb);

    conv_mfma<<<1280, 256, 0, stream>>>(xr, wb, Y);

    suffix_ctx<<<16, 512, 0, stream>>>(Y, bconv, out);

    attn_phase2<<<256, 512, 0, stream>>>(Y, bconv, out);
}